// Round 1
// baseline (720.048 us; speedup 1.0000x reference)
//
#include <hip/hip_runtime.h>
#include <hip/hip_bf16.h>
#include <cmath>

// Problem constants
#define BB 64
#define TT 2048
#define EE 1024
#define DD 1024
#define FAN 2048

typedef __attribute__((ext_vector_type(8))) short bhalf8;
typedef __attribute__((ext_vector_type(4))) float fvec4;

// ws layout (bytes)
#define OFF_WE   0u          // 2 MB  : We bf16, pre-swizzled [ec][eo][d][8]
#define OFF_C    2097152u    // 256 KB: c[b,d] = dec·Wd + bias
#define OFF_S    2359296u    // 512 KB: scores[b,t]
#define OFF_A    2883584u    // 512 KB: alpha[b,t]
#define OFF_P    3407872u    // 4 MB  : context partials [16][64][1024]

__device__ __forceinline__ short f2bf(float f) {
    unsigned int u = __float_as_uint(f);
    u += 0x7FFFu + ((u >> 16) & 1u);   // round-to-nearest-even
    return (short)(u >> 16);
}

__device__ __forceinline__ void gload_lds16(const void* g, void* l) {
    __builtin_amdgcn_global_load_lds(
        (const __attribute__((address_space(1))) void*)g,
        (__attribute__((address_space(3))) void*)l,
        16, 0, 0);
}

// ---------------- kernel 0a: convert We (f32) -> pre-swizzled bf16 image ----
// image layout per 32-wide e-chunk ec: byte = ec*65536 + eo*16384 + d*16 + r*2
__global__ void prep_we_k(const float* __restrict__ W, short* __restrict__ wsWe) {
    int g  = blockIdx.x * 256 + threadIdx.x;   // 0..131071
    int ec = g >> 12;          // 0..31
    int eo = (g >> 10) & 3;    // 0..3
    int d  = g & 1023;
    const float* src = W + (size_t)d * FAN + ec * 32 + eo * 8;
    float4 f0 = *(const float4*)src;
    float4 f1 = *(const float4*)(src + 4);
    bhalf8 h;
    h[0] = f2bf(f0.x); h[1] = f2bf(f0.y); h[2] = f2bf(f0.z); h[3] = f2bf(f0.w);
    h[4] = f2bf(f1.x); h[5] = f2bf(f1.y); h[6] = f2bf(f1.z); h[7] = f2bf(f1.w);
    *(bhalf8*)((char*)wsWe + (size_t)ec * 65536 + eo * 16384 + d * 16) = h;
}

// ---------------- kernel 0b: c[b,d] = dec[b,:]·Wd[d,:] + bias[d] ------------
__global__ void prep_c_k(const float* __restrict__ W, const float* __restrict__ bias,
                         const float* __restrict__ dec, float* __restrict__ cbuf) {
    int wg   = blockIdx.x * 4 + (threadIdx.x >> 6);  // 0..65535
    int lane = threadIdx.x & 63;
    int b = wg >> 10, d = wg & 1023;
    const float* wrow = W + (size_t)d * FAN + EE;    // Wd part
    const float* drow = dec + b * DD;
    float p = 0.f;
#pragma unroll
    for (int i = 0; i < 16; ++i)
        p += wrow[i * 64 + lane] * drow[i * 64 + lane];
#pragma unroll
    for (int off = 1; off < 64; off <<= 1)
        p += __shfl_xor(p, off);
    if (lane == 0) cbuf[b * DD + d] = p + bias[d];
}

// ---------------- kernel 1: scores[b,t] = v · tanh(enc·We^T + c) ------------
// block: 512 thr (8 waves), computes 64 t-rows x full 1024 d. Wave w owns
// d in [w*128, w*128+128). grid = (32 t-tiles, 64 b).
__global__ __launch_bounds__(512, 2)
void scores_k(const float* __restrict__ enc, const short* __restrict__ wsWe,
              const float* __restrict__ cbuf, const float* __restrict__ vw,
              float* __restrict__ scores) {
    __shared__ short sB[4][1024][8];   // 64 KB  [eo][d][8e]
    __shared__ short sA[4][64][8];     // 4 KB   [eo][t][8e]
    __shared__ float sRed[8][64];      // 2 KB

    const int tid  = threadIdx.x;
    const int w    = tid >> 6;
    const int lane = tid & 63;
    const int lrow = lane >> 4;   // 0..3 (e-octet)
    const int lcol = lane & 15;
    const int b  = blockIdx.y;
    const int t0 = blockIdx.x * 64;

    fvec4 acc[4][8];
#pragma unroll
    for (int m = 0; m < 4; ++m)
#pragma unroll
        for (int n = 0; n < 8; ++n)
            acc[m][n] = (fvec4){0.f, 0.f, 0.f, 0.f};

    float cv[8], vv[8];
#pragma unroll
    for (int n = 0; n < 8; ++n) {
        int d = w * 128 + n * 16 + lcol;
        cv[n] = cbuf[b * DD + d];
        vv[n] = vw[d];
    }

    const int tA  = tid & 63;   // staging thread -> t row (tid < 256)
    const int eoA = tid >> 6;   // -> e-octet (0..3)

    for (int ks = 0; ks < 32; ++ks) {
        // stage A (64t x 32e, fp32 -> bf16), threads 0..255, conflict-free writes
        if (tid < 256) {
            const float* src = enc + ((size_t)(b * TT + t0 + tA)) * EE + ks * 32 + eoA * 8;
            float4 f0 = *(const float4*)src;
            float4 f1 = *(const float4*)(src + 4);
            bhalf8 h;
            h[0] = f2bf(f0.x); h[1] = f2bf(f0.y); h[2] = f2bf(f0.z); h[3] = f2bf(f0.w);
            h[4] = f2bf(f1.x); h[5] = f2bf(f1.y); h[6] = f2bf(f1.z); h[7] = f2bf(f1.w);
            *(bhalf8*)&sA[eoA][tA][0] = h;
        }
        // stage B (1024d x 32e bf16) via async global->LDS, linear 64KB copy
        {
            const char* gs = (const char*)wsWe + (size_t)ks * 65536 + w * 8192;
            char* ls = (char*)&sB[0][0][0] + w * 8192;
#pragma unroll
            for (int i = 0; i < 8; ++i)
                gload_lds16(gs + i * 1024 + lane * 16, ls + i * 1024);
        }
        __syncthreads();

        bhalf8 af[4];
#pragma unroll
        for (int m = 0; m < 4; ++m)
            af[m] = *(const bhalf8*)&sA[lrow][m * 16 + lcol][0];
#pragma unroll
        for (int n = 0; n < 8; ++n) {
            bhalf8 bf = *(const bhalf8*)&sB[lrow][w * 128 + n * 16 + lcol][0];
#pragma unroll
            for (int m = 0; m < 4; ++m)
                acc[m][n] = __builtin_amdgcn_mfma_f32_16x16x32_bf16(af[m], bf, acc[m][n], 0, 0, 0);
        }
        __syncthreads();
    }

    // epilogue: tanh + v-dot, reduce over d
#pragma unroll
    for (int m = 0; m < 4; ++m) {
#pragma unroll
        for (int j = 0; j < 4; ++j) {
            float p = 0.f;
#pragma unroll
            for (int n = 0; n < 8; ++n)
                p += vv[n] * tanhf(acc[m][n][j] + cv[n]);
            p += __shfl_xor(p, 1); p += __shfl_xor(p, 2);
            p += __shfl_xor(p, 4); p += __shfl_xor(p, 8);
            if (lcol == 0) sRed[w][m * 16 + lrow * 4 + j] = p;
        }
    }
    __syncthreads();
    if (tid < 64) {
        float s = 0.f;
#pragma unroll
        for (int w2 = 0; w2 < 8; ++w2) s += sRed[w2][tid];
        scores[b * TT + t0 + tid] = s;
    }
}

// ---------------- kernel 2: softmax over t per batch ------------------------
__global__ void softmax_k(const float* __restrict__ scores, float* __restrict__ alpha) {
    int b = blockIdx.x, tid = threadIdx.x;
    float s[8];
    float m = -1e30f;
#pragma unroll
    for (int i = 0; i < 8; ++i) {
        s[i] = scores[b * TT + i * 256 + tid];
        m = fmaxf(m, s[i]);
    }
#pragma unroll
    for (int off = 1; off < 64; off <<= 1) m = fmaxf(m, __shfl_xor(m, off));
    __shared__ float red[4], red2[4];
    if ((tid & 63) == 0) red[tid >> 6] = m;
    __syncthreads();
    m = fmaxf(fmaxf(red[0], red[1]), fmaxf(red[2], red[3]));
    float sum = 0.f;
#pragma unroll
    for (int i = 0; i < 8; ++i) { s[i] = expf(s[i] - m); sum += s[i]; }
#pragma unroll
    for (int off = 1; off < 64; off <<= 1) sum += __shfl_xor(sum, off);
    if ((tid & 63) == 0) red2[tid >> 6] = sum;
    __syncthreads();
    sum = red2[0] + red2[1] + red2[2] + red2[3];
    float inv = 1.0f / sum;
#pragma unroll
    for (int i = 0; i < 8; ++i) alpha[b * TT + i * 256 + tid] = s[i] * inv;
}

// ---------------- kernel 3: context partials over t-slices ------------------
// grid (16 t-slices, 64 b), 256 thr, each thread owns 4 consecutive e
__global__ void ctx_k(const float* __restrict__ enc, const float* __restrict__ alpha,
                      float* __restrict__ part) {
    int ts = blockIdx.x, b = blockIdx.y, tid = threadIdx.x;
    __shared__ float sAl[128];
    if (tid < 128) sAl[tid] = alpha[b * TT + ts * 128 + tid];
    __syncthreads();
    float4 acc = {0.f, 0.f, 0.f, 0.f};
    const float* base = enc + ((size_t)b * TT + ts * 128) * EE + tid * 4;
#pragma unroll 8
    for (int i = 0; i < 128; ++i) {
        float4 v = *(const float4*)(base + (size_t)i * EE);
        float a = sAl[i];
        acc.x += a * v.x; acc.y += a * v.y; acc.z += a * v.z; acc.w += a * v.w;
    }
    *(float4*)&part[(size_t)(ts * 64 + b) * EE + tid * 4] = acc;
}

// ---------------- kernel 4: combine partials --------------------------------
__global__ void comb_k(const float* __restrict__ part, float* __restrict__ out) {
    int g = blockIdx.x * 256 + threadIdx.x;   // 0..65535
    float s = 0.f;
#pragma unroll
    for (int ts = 0; ts < 16; ++ts) s += part[(size_t)ts * 65536 + g];
    out[g] = s;
}

extern "C" void kernel_launch(void* const* d_in, const int* in_sizes, int n_in,
                              void* d_out, int out_size, void* d_ws, size_t ws_size,
                              hipStream_t stream) {
    const float* enc  = (const float*)d_in[0];
    const float* dec  = (const float*)d_in[1];
    const float* W    = (const float*)d_in[2];
    const float* bias = (const float*)d_in[3];
    const float* vw   = (const float*)d_in[4];
    float* out = (float*)d_out;

    char* ws = (char*)d_ws;
    short* wsWe   = (short*)(ws + OFF_WE);
    float* cbuf   = (float*)(ws + OFF_C);
    float* scores = (float*)(ws + OFF_S);
    float* alpha  = (float*)(ws + OFF_A);
    float* part   = (float*)(ws + OFF_P);

    prep_we_k<<<512, 256, 0, stream>>>(W, wsWe);
    prep_c_k<<<16384, 256, 0, stream>>>(W, bias, dec, cbuf);
    scores_k<<<dim3(32, 64), 512, 0, stream>>>(enc, wsWe, cbuf, vw, scores);
    softmax_k<<<64, 256, 0, stream>>>(scores, alpha);
    ctx_k<<<dim3(16, 64), 256, 0, stream>>>(enc, alpha, part);
    comb_k<<<256, 256, 0, stream>>>(part, out);
}

// Round 2
// 642.602 us; speedup vs baseline: 1.1205x; 1.1205x over previous
//
#include <hip/hip_runtime.h>
#include <hip/hip_bf16.h>
#include <cmath>

// Problem constants
#define BB 64
#define TT 2048
#define EE 1024
#define DD 1024
#define FAN 2048

typedef __attribute__((ext_vector_type(8))) short bhalf8;
typedef __attribute__((ext_vector_type(4))) float fvec4;

// ws layout (bytes)
#define OFF_WE   0u          // 2 MB  : We bf16, pre-swizzled [ec][eo][d][8]
#define OFF_C    2097152u    // 256 KB: c[b,d] = dec·Wd + bias
#define OFF_S    2359296u    // 512 KB: scores[b,t]
#define OFF_A    2883584u    // 512 KB: alpha[b,t]
#define OFF_P    3407872u    // 4 MB  : context partials [16][64][1024]

__device__ __forceinline__ short f2bf(float f) {
    unsigned int u = __float_as_uint(f);
    u += 0x7FFFu + ((u >> 16) & 1u);   // round-to-nearest-even
    return (short)(u >> 16);
}

// ---------------- kernel 0a: convert We (f32) -> pre-swizzled bf16 image ----
// image layout per 32-wide e-chunk ec: byte = ec*65536 + eo*16384 + d*16 + r*2
__global__ void prep_we_k(const float* __restrict__ W, short* __restrict__ wsWe) {
    int g  = blockIdx.x * 256 + threadIdx.x;   // 0..131071
    int ec = g >> 12;          // 0..31
    int eo = (g >> 10) & 3;    // 0..3
    int d  = g & 1023;
    const float* src = W + (size_t)d * FAN + ec * 32 + eo * 8;
    float4 f0 = *(const float4*)src;
    float4 f1 = *(const float4*)(src + 4);
    bhalf8 h;
    h[0] = f2bf(f0.x); h[1] = f2bf(f0.y); h[2] = f2bf(f0.z); h[3] = f2bf(f0.w);
    h[4] = f2bf(f1.x); h[5] = f2bf(f1.y); h[6] = f2bf(f1.z); h[7] = f2bf(f1.w);
    *(bhalf8*)((char*)wsWe + (size_t)ec * 65536 + eo * 16384 + d * 16) = h;
}

// ---------------- kernel 0b: c[b,d] = dec[b,:]·Wd[d,:] + bias[d] ------------
__global__ void prep_c_k(const float* __restrict__ W, const float* __restrict__ bias,
                         const float* __restrict__ dec, float* __restrict__ cbuf) {
    int wg   = blockIdx.x * 4 + (threadIdx.x >> 6);  // 0..65535
    int lane = threadIdx.x & 63;
    int b = wg >> 10, d = wg & 1023;
    const float* wrow = W + (size_t)d * FAN + EE;    // Wd part
    const float* drow = dec + b * DD;
    float p = 0.f;
#pragma unroll
    for (int i = 0; i < 16; ++i)
        p += wrow[i * 64 + lane] * drow[i * 64 + lane];
#pragma unroll
    for (int off = 1; off < 64; off <<= 1)
        p += __shfl_xor(p, off);
    if (lane == 0) cbuf[b * DD + d] = p + bias[d];
}

// ---------------- kernel 1: scores[b,t] = v · tanh(enc·We^T + c) ------------
// block: 512 thr (8 waves), 64 t-rows x full 1024 d. Wave w owns d-slice
// [w*128, w*128+128). A-tile staged ONCE into LDS (128 KB, XOR-swizzled);
// B fragments loaded directly from L2-resident pre-swizzled We image.
// K-loop has NO barriers.
__global__ __launch_bounds__(512, 2)
void scores_k(const float* __restrict__ enc, const short* __restrict__ wsWe,
              const float* __restrict__ cbuf, const float* __restrict__ vw,
              float* __restrict__ scores) {
    __shared__ short sA[64 * 1024];    // 128 KB, row-major [t][e], XOR-swizzled
    __shared__ float sRed[8][64];      // 2 KB

    const int tid  = threadIdx.x;
    const int w    = tid >> 6;
    const int lane = tid & 63;
    const int lrow = lane >> 4;   // 0..3 (e-octet within 32-chunk)
    const int lcol = lane & 15;
    const int b  = blockIdx.y;
    const int t0 = blockIdx.x * 64;

    // ---- stage full A tile: fp32 -> bf16, coalesced reads, swizzled writes
    // swizzle: byte(t, eb) = t*2048 + (eb ^ ((t&7)<<4))
#pragma unroll
    for (int it = 0; it < 16; ++it) {
        int idx = it * 512 + tid;         // 0..8191
        int t   = idx >> 7;               // 0..63
        int c   = idx & 127;              // 16B-chunk within row
        const float* src = enc + ((size_t)(b * TT + t0 + t)) * EE + c * 8;
        float4 f0 = *(const float4*)src;
        float4 f1 = *(const float4*)(src + 4);
        bhalf8 h;
        h[0] = f2bf(f0.x); h[1] = f2bf(f0.y); h[2] = f2bf(f0.z); h[3] = f2bf(f0.w);
        h[4] = f2bf(f1.x); h[5] = f2bf(f1.y); h[6] = f2bf(f1.z); h[7] = f2bf(f1.w);
        int eb = (c * 16) ^ ((t & 7) << 4);
        *(bhalf8*)((char*)sA + t * 2048 + eb) = h;
    }
    __syncthreads();

    fvec4 acc[4][8];
#pragma unroll
    for (int m = 0; m < 4; ++m)
#pragma unroll
        for (int n = 0; n < 8; ++n)
            acc[m][n] = (fvec4){0.f, 0.f, 0.f, 0.f};

    // per-lane B base into the pre-swizzled image: eo=lrow, d = w*128 + lcol
    const char* Bp = (const char*)wsWe + lrow * 16384 + (w * 128 + lcol) * 16;

    // A frag byte addresses (per m), constant over ks except the ks term
    int aoff[4];
#pragma unroll
    for (int m = 0; m < 4; ++m) {
        int t = m * 16 + lcol;
        aoff[m] = t * 2048 + ((lrow * 16) ^ ((t & 7) << 4));
    }

    for (int ks = 0; ks < 32; ++ks) {
        bhalf8 bf[8];
#pragma unroll
        for (int n = 0; n < 8; ++n)
            bf[n] = *(const bhalf8*)(Bp + (size_t)ks * 65536 + n * 256);
        bhalf8 af[4];
#pragma unroll
        for (int m = 0; m < 4; ++m) {
            int t = m * 16 + lcol;
            int eb = (ks * 64 + lrow * 16) ^ ((t & 7) << 4);
            af[m] = *(const bhalf8*)((const char*)sA + t * 2048 + eb);
        }
#pragma unroll
        for (int n = 0; n < 8; ++n)
#pragma unroll
            for (int m = 0; m < 4; ++m)
                acc[m][n] = __builtin_amdgcn_mfma_f32_16x16x32_bf16(af[m], bf[n], acc[m][n], 0, 0, 0);
    }

    float cv[8], vv[8];
#pragma unroll
    for (int n = 0; n < 8; ++n) {
        int d = w * 128 + n * 16 + lcol;
        cv[n] = cbuf[b * DD + d];
        vv[n] = vw[d];
    }

    // epilogue: tanh + v-dot, reduce over d
#pragma unroll
    for (int m = 0; m < 4; ++m) {
#pragma unroll
        for (int j = 0; j < 4; ++j) {
            float p = 0.f;
#pragma unroll
            for (int n = 0; n < 8; ++n)
                p += vv[n] * tanhf(acc[m][n][j] + cv[n]);
            p += __shfl_xor(p, 1); p += __shfl_xor(p, 2);
            p += __shfl_xor(p, 4); p += __shfl_xor(p, 8);
            if (lcol == 0) sRed[w][m * 16 + lrow * 4 + j] = p;
        }
    }
    __syncthreads();
    if (tid < 64) {
        float s = 0.f;
#pragma unroll
        for (int w2 = 0; w2 < 8; ++w2) s += sRed[w2][tid];
        scores[b * TT + t0 + tid] = s;
    }
}

// ---------------- kernel 2: softmax over t per batch ------------------------
__global__ void softmax_k(const float* __restrict__ scores, float* __restrict__ alpha) {
    int b = blockIdx.x, tid = threadIdx.x;
    float s[8];
    float m = -1e30f;
#pragma unroll
    for (int i = 0; i < 8; ++i) {
        s[i] = scores[b * TT + i * 256 + tid];
        m = fmaxf(m, s[i]);
    }
#pragma unroll
    for (int off = 1; off < 64; off <<= 1) m = fmaxf(m, __shfl_xor(m, off));
    __shared__ float red[4], red2[4];
    if ((tid & 63) == 0) red[tid >> 6] = m;
    __syncthreads();
    m = fmaxf(fmaxf(red[0], red[1]), fmaxf(red[2], red[3]));
    float sum = 0.f;
#pragma unroll
    for (int i = 0; i < 8; ++i) { s[i] = expf(s[i] - m); sum += s[i]; }
#pragma unroll
    for (int off = 1; off < 64; off <<= 1) sum += __shfl_xor(sum, off);
    if ((tid & 63) == 0) red2[tid >> 6] = sum;
    __syncthreads();
    sum = red2[0] + red2[1] + red2[2] + red2[3];
    float inv = 1.0f / sum;
#pragma unroll
    for (int i = 0; i < 8; ++i) alpha[b * TT + i * 256 + tid] = s[i] * inv;
}

// ---------------- kernel 3: context partials over t-slices ------------------
// grid (16 t-slices, 64 b), 256 thr, each thread owns 4 consecutive e
__global__ void ctx_k(const float* __restrict__ enc, const float* __restrict__ alpha,
                      float* __restrict__ part) {
    int ts = blockIdx.x, b = blockIdx.y, tid = threadIdx.x;
    __shared__ float sAl[128];
    if (tid < 128) sAl[tid] = alpha[b * TT + ts * 128 + tid];
    __syncthreads();
    float4 acc = {0.f, 0.f, 0.f, 0.f};
    const float* base = enc + ((size_t)b * TT + ts * 128) * EE + tid * 4;
#pragma unroll 8
    for (int i = 0; i < 128; ++i) {
        float4 v = *(const float4*)(base + (size_t)i * EE);
        float a = sAl[i];
        acc.x += a * v.x; acc.y += a * v.y; acc.z += a * v.z; acc.w += a * v.w;
    }
    *(float4*)&part[(size_t)(ts * 64 + b) * EE + tid * 4] = acc;
}

// ---------------- kernel 4: combine partials --------------------------------
__global__ void comb_k(const float* __restrict__ part, float* __restrict__ out) {
    int g = blockIdx.x * 256 + threadIdx.x;   // 0..65535
    float s = 0.f;
#pragma unroll
    for (int ts = 0; ts < 16; ++ts) s += part[(size_t)ts * 65536 + g];
    out[g] = s;
}

extern "C" void kernel_launch(void* const* d_in, const int* in_sizes, int n_in,
                              void* d_out, int out_size, void* d_ws, size_t ws_size,
                              hipStream_t stream) {
    const float* enc  = (const float*)d_in[0];
    const float* dec  = (const float*)d_in[1];
    const float* W    = (const float*)d_in[2];
    const float* bias = (const float*)d_in[3];
    const float* vw   = (const float*)d_in[4];
    float* out = (float*)d_out;

    char* ws = (char*)d_ws;
    short* wsWe   = (short*)(ws + OFF_WE);
    float* cbuf   = (float*)(ws + OFF_C);
    float* scores = (float*)(ws + OFF_S);
    float* alpha  = (float*)(ws + OFF_A);
    float* part   = (float*)(ws + OFF_P);

    prep_we_k<<<512, 256, 0, stream>>>(W, wsWe);
    prep_c_k<<<16384, 256, 0, stream>>>(W, bias, dec, cbuf);
    scores_k<<<dim3(32, 64), 512, 0, stream>>>(enc, wsWe, cbuf, vw, scores);
    softmax_k<<<64, 256, 0, stream>>>(scores, alpha);
    ctx_k<<<dim3(16, 64), 256, 0, stream>>>(enc, alpha, part);
    comb_k<<<256, 256, 0, stream>>>(part, out);
}

// Round 3
// 616.608 us; speedup vs baseline: 1.1678x; 1.0422x over previous
//
#include <hip/hip_runtime.h>
#include <hip/hip_bf16.h>
#include <cmath>

// Problem constants
#define BB 64
#define TT 2048
#define EE 1024
#define DD 1024
#define FAN 2048

typedef __attribute__((ext_vector_type(8))) short bhalf8;
typedef __attribute__((ext_vector_type(4))) float fvec4;

// ws layout (bytes)
#define OFF_WE   0u          // 2 MB  : We bf16, pre-swizzled [ec][eo][d][8]
#define OFF_C    2097152u    // 256 KB: c[b,d] = dec·Wd + bias
#define OFF_S    2359296u    // 512 KB: scores[b,t]
#define OFF_A    2883584u    // 512 KB: alpha[b,t]
#define OFF_P    3407872u    // 4 MB  : context partials [16][64][1024]

__device__ __forceinline__ short f2bf(float f) {
    unsigned int u = __float_as_uint(f);
    u += 0x7FFFu + ((u >> 16) & 1u);   // round-to-nearest-even
    return (short)(u >> 16);
}

__device__ __forceinline__ bhalf8 cvt8(float4 a, float4 b) {
    bhalf8 h;
    h[0] = f2bf(a.x); h[1] = f2bf(a.y); h[2] = f2bf(a.z); h[3] = f2bf(a.w);
    h[4] = f2bf(b.x); h[5] = f2bf(b.y); h[6] = f2bf(b.z); h[7] = f2bf(b.w);
    return h;
}

__device__ __forceinline__ float fast_tanhf(float x) {
    float ax = __builtin_fabsf(x);
    float e  = __expf(-2.0f * ax);
    float r  = (1.0f - e) * __builtin_amdgcn_rcpf(1.0f + e);
    return __builtin_copysignf(r, x);
}

// ---------------- kernel 0a: convert We (f32) -> pre-swizzled bf16 image ----
// image layout per 32-wide e-chunk ec: byte = ec*65536 + eo*16384 + d*16 + r*2
__global__ void prep_we_k(const float* __restrict__ W, short* __restrict__ wsWe) {
    int g  = blockIdx.x * 256 + threadIdx.x;   // 0..131071
    int ec = g >> 12;          // 0..31
    int eo = (g >> 10) & 3;    // 0..3
    int d  = g & 1023;
    const float* src = W + (size_t)d * FAN + ec * 32 + eo * 8;
    float4 f0 = *(const float4*)src;
    float4 f1 = *(const float4*)(src + 4);
    *(bhalf8*)((char*)wsWe + (size_t)ec * 65536 + eo * 16384 + d * 16) = cvt8(f0, f1);
}

// ---------------- kernel 0b: c[b,d] = dec[b,:]·Wd[d,:] + bias[d] ------------
__global__ void prep_c_k(const float* __restrict__ W, const float* __restrict__ bias,
                         const float* __restrict__ dec, float* __restrict__ cbuf) {
    int wg   = blockIdx.x * 4 + (threadIdx.x >> 6);  // 0..65535
    int lane = threadIdx.x & 63;
    int b = wg >> 10, d = wg & 1023;
    const float* wrow = W + (size_t)d * FAN + EE;    // Wd part
    const float* drow = dec + b * DD;
    float p = 0.f;
#pragma unroll
    for (int i = 0; i < 16; ++i)
        p += wrow[i * 64 + lane] * drow[i * 64 + lane];
#pragma unroll
    for (int off = 1; off < 64; off <<= 1)
        p += __shfl_xor(p, off);
    if (lane == 0) cbuf[b * DD + d] = p + bias[d];
}

// ---------------- kernel 1: scores[b,t] = v · tanh(enc·We^T + c) ------------
// 512 thr (8 waves), tile 64 t x 1024 d, wave w owns d-slice [w*128, +128).
// K-loop: BK=64 chunks, LDS double-buffer (2 x 8KB, fragment-contiguous
// [eo][t][8] layout = 0 bank conflicts), depth-2 register prefetch of the
// fp32 A chunk (issue at step i, cvt+ds_write at step i end for chunk i+1,
// consumed at step i+1) — T14/T3 2-phase template. B frags stream from the
// L2-resident pre-swizzled We image straight to registers.
__global__ __launch_bounds__(512, 2)
void scores_k(const float* __restrict__ enc, const short* __restrict__ wsWe,
              const float* __restrict__ cbuf, const float* __restrict__ vw,
              float* __restrict__ scores) {
    __shared__ short sA[2][8][64][8];   // 16 KB: [buf][eo][t][8e] bf16
    __shared__ float sRed[8][64];       // 2 KB

    const int tid  = threadIdx.x;
    const int w    = tid >> 6;
    const int lane = tid & 63;
    const int lrow = lane >> 4;   // 0..3
    const int lcol = lane & 15;
    const int b  = blockIdx.y;
    const int t0 = blockIdx.x * 64;

    // staging assignment: thread -> (t row, e-octet), one bhalf8 per step
    const int st  = tid >> 3;     // 0..63
    const int seo = tid & 7;      // 0..7
    const float* gsrc = enc + ((size_t)(b * TT + t0 + st)) * EE + seo * 8;

    fvec4 acc[4][8];
#pragma unroll
    for (int m = 0; m < 4; ++m)
#pragma unroll
        for (int n = 0; n < 8; ++n)
            acc[m][n] = (fvec4){0.f, 0.f, 0.f, 0.f};

    // per-lane B base into the pre-swizzled image (eo=lrow, d=w*128+lcol)
    const char* Bbase = (const char*)wsWe + lrow * 16384 + (w * 128 + lcol) * 16;

    // ---- prologue: load chunk0 -> set0, chunk1 -> set1; write chunk0
    float4 rA0 = *(const float4*)(gsrc);
    float4 rA1 = *(const float4*)(gsrc + 4);
    float4 rB0 = *(const float4*)(gsrc + 64);
    float4 rB1 = *(const float4*)(gsrc + 68);
    *(bhalf8*)&sA[0][seo][st][0] = cvt8(rA0, rA1);
    __syncthreads();

#pragma unroll 2
    for (int i = 0; i < 16; ++i) {
        // (1) issue global loads for chunk i+2 into the freed register set
        if (i + 2 < 16) {
            if ((i & 1) == 0) {
                rA0 = *(const float4*)(gsrc + (i + 2) * 64);
                rA1 = *(const float4*)(gsrc + (i + 2) * 64 + 4);
            } else {
                rB0 = *(const float4*)(gsrc + (i + 2) * 64);
                rB1 = *(const float4*)(gsrc + (i + 2) * 64 + 4);
            }
        }
        // (2) compute chunk i from sA[i&1]
        const short* Ab = &sA[i & 1][0][0][0];
#pragma unroll
        for (int kk = 0; kk < 2; ++kk) {
            bhalf8 bf[8];
#pragma unroll
            for (int n = 0; n < 8; ++n)
                bf[n] = *(const bhalf8*)(Bbase + (size_t)(2 * i + kk) * 65536 + n * 256);
            bhalf8 af[4];
#pragma unroll
            for (int m = 0; m < 4; ++m)
                af[m] = *(const bhalf8*)(Ab + ((kk * 4 + lrow) * 64 + m * 16 + lcol) * 8);
#pragma unroll
            for (int n = 0; n < 8; ++n)
#pragma unroll
                for (int m = 0; m < 4; ++m)
                    acc[m][n] = __builtin_amdgcn_mfma_f32_16x16x32_bf16(af[m], bf[n], acc[m][n], 0, 0, 0);
        }
        // (3) cvt + write chunk i+1 into the other LDS buffer
        if (i < 15) {
            bhalf8 h = ((i & 1) == 0) ? cvt8(rB0, rB1) : cvt8(rA0, rA1);
            *(bhalf8*)&sA[(i + 1) & 1][seo][st][0] = h;
        }
        __syncthreads();
    }

    float cv[8], vv[8];
#pragma unroll
    for (int n = 0; n < 8; ++n) {
        int d = w * 128 + n * 16 + lcol;
        cv[n] = cbuf[b * DD + d];
        vv[n] = vw[d];
    }

    // epilogue: tanh + v-dot, reduce over d
#pragma unroll
    for (int m = 0; m < 4; ++m) {
#pragma unroll
        for (int j = 0; j < 4; ++j) {
            float p = 0.f;
#pragma unroll
            for (int n = 0; n < 8; ++n)
                p += vv[n] * fast_tanhf(acc[m][n][j] + cv[n]);
            p += __shfl_xor(p, 1); p += __shfl_xor(p, 2);
            p += __shfl_xor(p, 4); p += __shfl_xor(p, 8);
            if (lcol == 0) sRed[w][m * 16 + lrow * 4 + j] = p;
        }
    }
    __syncthreads();
    if (tid < 64) {
        float s = 0.f;
#pragma unroll
        for (int w2 = 0; w2 < 8; ++w2) s += sRed[w2][tid];
        scores[b * TT + t0 + tid] = s;
    }
}

// ---------------- kernel 2: softmax over t per batch ------------------------
__global__ void softmax_k(const float* __restrict__ scores, float* __restrict__ alpha) {
    int b = blockIdx.x, tid = threadIdx.x;
    float s[8];
    float m = -1e30f;
#pragma unroll
    for (int i = 0; i < 8; ++i) {
        s[i] = scores[b * TT + i * 256 + tid];
        m = fmaxf(m, s[i]);
    }
#pragma unroll
    for (int off = 1; off < 64; off <<= 1) m = fmaxf(m, __shfl_xor(m, off));
    __shared__ float red[4], red2[4];
    if ((tid & 63) == 0) red[tid >> 6] = m;
    __syncthreads();
    m = fmaxf(fmaxf(red[0], red[1]), fmaxf(red[2], red[3]));
    float sum = 0.f;
#pragma unroll
    for (int i = 0; i < 8; ++i) { s[i] = expf(s[i] - m); sum += s[i]; }
#pragma unroll
    for (int off = 1; off < 64; off <<= 1) sum += __shfl_xor(sum, off);
    if ((tid & 63) == 0) red2[tid >> 6] = sum;
    __syncthreads();
    sum = red2[0] + red2[1] + red2[2] + red2[3];
    float inv = 1.0f / sum;
#pragma unroll
    for (int i = 0; i < 8; ++i) alpha[b * TT + i * 256 + tid] = s[i] * inv;
}

// ---------------- kernel 3: context partials over t-slices ------------------
// grid (16 t-slices, 64 b), 256 thr, each thread owns 4 consecutive e
__global__ void ctx_k(const float* __restrict__ enc, const float* __restrict__ alpha,
                      float* __restrict__ part) {
    int ts = blockIdx.x, b = blockIdx.y, tid = threadIdx.x;
    __shared__ float sAl[128];
    if (tid < 128) sAl[tid] = alpha[b * TT + ts * 128 + tid];
    __syncthreads();
    float4 acc = {0.f, 0.f, 0.f, 0.f};
    const float* base = enc + ((size_t)b * TT + ts * 128) * EE + tid * 4;
#pragma unroll 8
    for (int i = 0; i < 128; ++i) {
        float4 v = *(const float4*)(base + (size_t)i * EE);
        float a = sAl[i];
        acc.x += a * v.x; acc.y += a * v.y; acc.z += a * v.z; acc.w += a * v.w;
    }
    *(float4*)&part[(size_t)(ts * 64 + b) * EE + tid * 4] = acc;
}

// ---------------- kernel 4: combine partials --------------------------------
__global__ void comb_k(const float* __restrict__ part, float* __restrict__ out) {
    int g = blockIdx.x * 256 + threadIdx.x;   // 0..65535
    float s = 0.f;
#pragma unroll
    for (int ts = 0; ts < 16; ++ts) s += part[(size_t)ts * 65536 + g];
    out[g] = s;
}

extern "C" void kernel_launch(void* const* d_in, const int* in_sizes, int n_in,
                              void* d_out, int out_size, void* d_ws, size_t ws_size,
                              hipStream_t stream) {
    const float* enc  = (const float*)d_in[0];
    const float* dec  = (const float*)d_in[1];
    const float* W    = (const float*)d_in[2];
    const float* bias = (const float*)d_in[3];
    const float* vw   = (const float*)d_in[4];
    float* out = (float*)d_out;

    char* ws = (char*)d_ws;
    short* wsWe   = (short*)(ws + OFF_WE);
    float* cbuf   = (float*)(ws + OFF_C);
    float* scores = (float*)(ws + OFF_S);
    float* alpha  = (float*)(ws + OFF_A);
    float* part   = (float*)(ws + OFF_P);

    prep_we_k<<<512, 256, 0, stream>>>(W, wsWe);
    prep_c_k<<<16384, 256, 0, stream>>>(W, bias, dec, cbuf);
    scores_k<<<dim3(32, 64), 512, 0, stream>>>(enc, wsWe, cbuf, vw, scores);
    softmax_k<<<64, 256, 0, stream>>>(scores, alpha);
    ctx_k<<<dim3(16, 64), 256, 0, stream>>>(enc, alpha, part);
    comb_k<<<256, 256, 0, stream>>>(part, out);
}

// Round 4
// 481.734 us; speedup vs baseline: 1.4947x; 1.2800x over previous
//
#include <hip/hip_runtime.h>
#include <hip/hip_bf16.h>
#include <cmath>

// Problem constants
#define BB 64
#define TT 2048
#define EE 1024
#define DD 1024
#define FAN 2048

typedef __attribute__((ext_vector_type(8))) short bhalf8;
typedef __attribute__((ext_vector_type(4))) float fvec4;

// ws layout (bytes)
#define OFF_WE   0u          // 2 MB  : We bf16, pre-swizzled [ec][eo][d][8]
#define OFF_C    2097152u    // 256 KB: c[b,d] = dec·Wd + bias
#define OFF_S    2359296u    // 512 KB: scores[b,t]
#define OFF_A    2883584u    // 512 KB: alpha[b,t]
#define OFF_P    3407872u    // 4 MB  : context partials [16][64][1024]

__device__ __forceinline__ short f2bf(float f) {
    unsigned int u = __float_as_uint(f);
    u += 0x7FFFu + ((u >> 16) & 1u);   // round-to-nearest-even
    return (short)(u >> 16);
}

__device__ __forceinline__ bhalf8 cvt8(float4 a, float4 b) {
    bhalf8 h;
    h[0] = f2bf(a.x); h[1] = f2bf(a.y); h[2] = f2bf(a.z); h[3] = f2bf(a.w);
    h[4] = f2bf(b.x); h[5] = f2bf(b.y); h[6] = f2bf(b.z); h[7] = f2bf(b.w);
    return h;
}

__device__ __forceinline__ float fast_tanhf(float x) {
    float ax = __builtin_fabsf(x);
    float e  = __expf(-2.0f * ax);
    float r  = (1.0f - e) * __builtin_amdgcn_rcpf(1.0f + e);
    return __builtin_copysignf(r, x);
}

// ---------------- kernel 0a: convert We (f32) -> pre-swizzled bf16 image ----
// image layout per 32-wide e-chunk ec: byte = ec*65536 + eo*16384 + d*16 + r*2
__global__ void prep_we_k(const float* __restrict__ W, short* __restrict__ wsWe) {
    int g  = blockIdx.x * 256 + threadIdx.x;   // 0..131071
    int ec = g >> 12;          // 0..31
    int eo = (g >> 10) & 3;    // 0..3
    int d  = g & 1023;
    const float* src = W + (size_t)d * FAN + ec * 32 + eo * 8;
    float4 f0 = *(const float4*)src;
    float4 f1 = *(const float4*)(src + 4);
    *(bhalf8*)((char*)wsWe + (size_t)ec * 65536 + eo * 16384 + d * 16) = cvt8(f0, f1);
}

// ---------------- kernel 0b: c[b,d] = dec[b,:]·Wd[d,:] + bias[d] ------------
__global__ void prep_c_k(const float* __restrict__ W, const float* __restrict__ bias,
                         const float* __restrict__ dec, float* __restrict__ cbuf) {
    int wg   = blockIdx.x * 4 + (threadIdx.x >> 6);  // 0..65535
    int lane = threadIdx.x & 63;
    int b = wg >> 10, d = wg & 1023;
    const float* wrow = W + (size_t)d * FAN + EE;    // Wd part
    const float* drow = dec + b * DD;
    float p = 0.f;
#pragma unroll
    for (int i = 0; i < 16; ++i)
        p += wrow[i * 64 + lane] * drow[i * 64 + lane];
#pragma unroll
    for (int off = 1; off < 64; off <<= 1)
        p += __shfl_xor(p, off);
    if (lane == 0) cbuf[b * DD + d] = p + bias[d];
}

// ---------------- kernel 1: scores[b,t] = v · tanh(enc·We^T + c) ------------
// 512 thr (8 waves), tile 64 t x 1024 d, wave w owns d-slice [w*128, +128).
// BK=64 double-buffered A chunks in LDS, XOR-swizzled (t' = t ^ eo) so the
// staging ds_write is bank-conflict-free while global reads stay coalesced.
// B frags register-prefetched one half-step ahead from the L2-resident
// pre-swizzled We image. One barrier per step; vmcnt drain lands after the
// MFMA cluster (covered).
__global__ __launch_bounds__(512, 2)
void scores_k(const float* __restrict__ enc, const short* __restrict__ wsWe,
              const float* __restrict__ cbuf, const float* __restrict__ vw,
              float* __restrict__ scores) {
    __shared__ short sA[2][8][64][8];   // 16 KB: [buf][eo][t^eo][8e]
    __shared__ float sRed[8][64];       // 2 KB

    const int tid  = threadIdx.x;
    const int w    = tid >> 6;
    const int lane = tid & 63;
    const int lrow = lane >> 4;   // 0..3
    const int lcol = lane & 15;
    const int b  = blockIdx.y;
    const int t0 = blockIdx.x * 64;

    // staging: thread -> (t row st, e-octet seo); 256B-contiguous global reads
    const int st  = tid >> 3;     // 0..63
    const int seo = tid & 7;      // 0..7
    const float* gsrc = enc + ((size_t)(b * TT + t0 + st)) * EE + seo * 8;

    fvec4 acc[4][8];
#pragma unroll
    for (int m = 0; m < 4; ++m)
#pragma unroll
        for (int n = 0; n < 8; ++n)
            acc[m][n] = (fvec4){0.f, 0.f, 0.f, 0.f};

    // per-lane B base (eo=lrow, d=w*128+lcol)
    const char* Bbase = (const char*)wsWe + lrow * 16384 + (w * 128 + lcol) * 16;

    bhalf8 bf0[8], bf1[8];
    // prologue: B frags for ks=0; A chunk 0 -> LDS
    {
#pragma unroll
        for (int n = 0; n < 8; ++n)
            bf0[n] = *(const bhalf8*)(Bbase + n * 256);
        float4 a0 = *(const float4*)(gsrc);
        float4 a1 = *(const float4*)(gsrc + 4);
        *(bhalf8*)&sA[0][seo][st ^ seo][0] = cvt8(a0, a1);
    }
    __syncthreads();

    float4 a0, a1;
#pragma unroll
    for (int i = 0; i < 15; ++i) {
        const int buf = i & 1, nbuf = buf ^ 1;
        // (1) A chunk i+1 global loads (consumed at step end)
        a0 = *(const float4*)(gsrc + (i + 1) * 64);
        a1 = *(const float4*)(gsrc + (i + 1) * 64 + 4);
        // (2) B frags ks=2i+1 (consumed after kk0 MFMAs)
#pragma unroll
        for (int n = 0; n < 8; ++n)
            bf1[n] = *(const bhalf8*)(Bbase + (size_t)(2 * i + 1) * 65536 + n * 256);
        // (3) kk=0: af reads + MFMA
        {
            bhalf8 af[4];
#pragma unroll
            for (int m = 0; m < 4; ++m) {
                int t = m * 16 + lcol;
                af[m] = *(const bhalf8*)&sA[buf][lrow][t ^ lrow][0];
            }
#pragma unroll
            for (int n = 0; n < 8; ++n)
#pragma unroll
                for (int m = 0; m < 4; ++m)
                    acc[m][n] = __builtin_amdgcn_mfma_f32_16x16x32_bf16(af[m], bf0[n], acc[m][n], 0, 0, 0);
        }
        // (4) B frags ks=2i+2 for next step (covered by kk1 MFMAs + barrier)
#pragma unroll
        for (int n = 0; n < 8; ++n)
            bf0[n] = *(const bhalf8*)(Bbase + (size_t)(2 * i + 2) * 65536 + n * 256);
        // (5) kk=1: af reads + MFMA
        {
            bhalf8 af[4];
#pragma unroll
            for (int m = 0; m < 4; ++m) {
                int t = m * 16 + lcol;
                int eo = 4 + lrow;
                af[m] = *(const bhalf8*)&sA[buf][eo][t ^ eo][0];
            }
#pragma unroll
            for (int n = 0; n < 8; ++n)
#pragma unroll
                for (int m = 0; m < 4; ++m)
                    acc[m][n] = __builtin_amdgcn_mfma_f32_16x16x32_bf16(af[m], bf1[n], acc[m][n], 0, 0, 0);
        }
        // (6) cvt + swizzled write of chunk i+1
        *(bhalf8*)&sA[nbuf][seo][st ^ seo][0] = cvt8(a0, a1);
        __syncthreads();
    }
    // final step i=15 (no staging, no barrier)
    {
#pragma unroll
        for (int n = 0; n < 8; ++n)
            bf1[n] = *(const bhalf8*)(Bbase + (size_t)31 * 65536 + n * 256);
        bhalf8 af[4];
#pragma unroll
        for (int m = 0; m < 4; ++m) {
            int t = m * 16 + lcol;
            af[m] = *(const bhalf8*)&sA[1][lrow][t ^ lrow][0];
        }
#pragma unroll
        for (int n = 0; n < 8; ++n)
#pragma unroll
            for (int m = 0; m < 4; ++m)
                acc[m][n] = __builtin_amdgcn_mfma_f32_16x16x32_bf16(af[m], bf0[n], acc[m][n], 0, 0, 0);
#pragma unroll
        for (int m = 0; m < 4; ++m) {
            int t = m * 16 + lcol;
            int eo = 4 + lrow;
            af[m] = *(const bhalf8*)&sA[1][eo][t ^ eo][0];
        }
#pragma unroll
        for (int n = 0; n < 8; ++n)
#pragma unroll
            for (int m = 0; m < 4; ++m)
                acc[m][n] = __builtin_amdgcn_mfma_f32_16x16x32_bf16(af[m], bf1[n], acc[m][n], 0, 0, 0);
    }

    float cv[8], vv[8];
#pragma unroll
    for (int n = 0; n < 8; ++n) {
        int d = w * 128 + n * 16 + lcol;
        cv[n] = cbuf[b * DD + d];
        vv[n] = vw[d];
    }

    // epilogue: tanh + v-dot, reduce over d
#pragma unroll
    for (int m = 0; m < 4; ++m) {
#pragma unroll
        for (int j = 0; j < 4; ++j) {
            float p = 0.f;
#pragma unroll
            for (int n = 0; n < 8; ++n)
                p += vv[n] * fast_tanhf(acc[m][n][j] + cv[n]);
            p += __shfl_xor(p, 1); p += __shfl_xor(p, 2);
            p += __shfl_xor(p, 4); p += __shfl_xor(p, 8);
            if (lcol == 0) sRed[w][m * 16 + lrow * 4 + j] = p;
        }
    }
    __syncthreads();
    if (tid < 64) {
        float s = 0.f;
#pragma unroll
        for (int w2 = 0; w2 < 8; ++w2) s += sRed[w2][tid];
        scores[b * TT + t0 + tid] = s;
    }
}

// ---------------- kernel 2: softmax over t per batch ------------------------
__global__ void softmax_k(const float* __restrict__ scores, float* __restrict__ alpha) {
    int b = blockIdx.x, tid = threadIdx.x;
    float s[8];
    float m = -1e30f;
#pragma unroll
    for (int i = 0; i < 8; ++i) {
        s[i] = scores[b * TT + i * 256 + tid];
        m = fmaxf(m, s[i]);
    }
#pragma unroll
    for (int off = 1; off < 64; off <<= 1) m = fmaxf(m, __shfl_xor(m, off));
    __shared__ float red[4], red2[4];
    if ((tid & 63) == 0) red[tid >> 6] = m;
    __syncthreads();
    m = fmaxf(fmaxf(red[0], red[1]), fmaxf(red[2], red[3]));
    float sum = 0.f;
#pragma unroll
    for (int i = 0; i < 8; ++i) { s[i] = expf(s[i] - m); sum += s[i]; }
#pragma unroll
    for (int off = 1; off < 64; off <<= 1) sum += __shfl_xor(sum, off);
    if ((tid & 63) == 0) red2[tid >> 6] = sum;
    __syncthreads();
    sum = red2[0] + red2[1] + red2[2] + red2[3];
    float inv = 1.0f / sum;
#pragma unroll
    for (int i = 0; i < 8; ++i) alpha[b * TT + i * 256 + tid] = s[i] * inv;
}

// ---------------- kernel 3: context partials over t-slices ------------------
// grid (16 t-slices, 64 b), 256 thr, each thread owns 4 consecutive e
__global__ void ctx_k(const float* __restrict__ enc, const float* __restrict__ alpha,
                      float* __restrict__ part) {
    int ts = blockIdx.x, b = blockIdx.y, tid = threadIdx.x;
    __shared__ float sAl[128];
    if (tid < 128) sAl[tid] = alpha[b * TT + ts * 128 + tid];
    __syncthreads();
    float4 acc = {0.f, 0.f, 0.f, 0.f};
    const float* base = enc + ((size_t)b * TT + ts * 128) * EE + tid * 4;
#pragma unroll 8
    for (int i = 0; i < 128; ++i) {
        float4 v = *(const float4*)(base + (size_t)i * EE);
        float a = sAl[i];
        acc.x += a * v.x; acc.y += a * v.y; acc.z += a * v.z; acc.w += a * v.w;
    }
    *(float4*)&part[(size_t)(ts * 64 + b) * EE + tid * 4] = acc;
}

// ---------------- kernel 4: combine partials --------------------------------
__global__ void comb_k(const float* __restrict__ part, float* __restrict__ out) {
    int g = blockIdx.x * 256 + threadIdx.x;   // 0..65535
    float s = 0.f;
#pragma unroll
    for (int ts = 0; ts < 16; ++ts) s += part[(size_t)ts * 65536 + g];
    out[g] = s;
}

extern "C" void kernel_launch(void* const* d_in, const int* in_sizes, int n_in,
                              void* d_out, int out_size, void* d_ws, size_t ws_size,
                              hipStream_t stream) {
    const float* enc  = (const float*)d_in[0];
    const float* dec  = (const float*)d_in[1];
    const float* W    = (const float*)d_in[2];
    const float* bias = (const float*)d_in[3];
    const float* vw   = (const float*)d_in[4];
    float* out = (float*)d_out;

    char* ws = (char*)d_ws;
    short* wsWe   = (short*)(ws + OFF_WE);
    float* cbuf   = (float*)(ws + OFF_C);
    float* scores = (float*)(ws + OFF_S);
    float* alpha  = (float*)(ws + OFF_A);
    float* part   = (float*)(ws + OFF_P);

    prep_we_k<<<512, 256, 0, stream>>>(W, wsWe);
    prep_c_k<<<16384, 256, 0, stream>>>(W, bias, dec, cbuf);
    scores_k<<<dim3(32, 64), 512, 0, stream>>>(enc, wsWe, cbuf, vw, scores);
    softmax_k<<<64, 256, 0, stream>>>(scores, alpha);
    ctx_k<<<dim3(16, 64), 256, 0, stream>>>(enc, alpha, part);
    comb_k<<<256, 256, 0, stream>>>(part, out);
}